// Round 17
// baseline (114.118 us; speedup 1.0000x reference)
//
#include <hip/hip_runtime.h>

#define N_NODES 50000
#define N_EDGES 1600000
#define CH 128
#define NB 196         // buckets of 256 nodes: bucket = col >> 8
#define CHUNK_E 8192
#define NCHUNK 196     // ceil(N_EDGES / CHUNK_E) = 196 (195.3)
#define GEMMB 782      // ceil(N_NODES / 64)
#define CAP 12288      // per-bucket region capacity (mean 8163, +45 sigma)
#define CURS 16        // cursor stride (ints): one counter per 64B line
#define PF 6           // gather: prefetched 8-edge batches (covers deg <= 48)

// ws layout (bytes), total ~23 MB:
#define WS_CURSOR  0         // cursor [NB*CURS] int (padded; zeroed per call)
#define WS_ROWPTR  16384     // rowptr [N+1] int
#define WS_DINV    216448    // dinv [N] f32
#define WS_SCL     416448    // scl [N] f32 (rowmax/127; k_sort folds dinv in)
#define WS_SRC     616448    // src [E] int (6.4MB, global CSR order)
#define WS_Q8      7016448   // q8 [N][128] biased-uint8 (6.4MB)
#define WS_BINS    13416448  // bins [NB][CAP] u32 = row | colLow<<16 (9.6MB)

typedef __bf16 bf16x8 __attribute__((ext_vector_type(8)));
typedef float f32x4 __attribute__((ext_vector_type(4)));

__device__ __forceinline__ unsigned int pack_bf16(float a, float b) {
    unsigned int ua = __builtin_bit_cast(unsigned int, a);
    unsigned int ub = __builtin_bit_cast(unsigned int, b);
    ua = (ua + 0x7FFFu + ((ua >> 16) & 1u)) >> 16;   // RNE
    ub = (ub + 0x7FFFu + ((ub >> 16) & 1u)) >> 16;
    return ua | (ub << 16);
}

__device__ __forceinline__ void acc4(unsigned int v, float sc, float* a) {
    a[0] = fmaf((float)(v & 0xFFu), sc, a[0]);          // v_cvt_f32_ubyte0
    a[1] = fmaf((float)((v >> 8) & 0xFFu), sc, a[1]);
    a[2] = fmaf((float)((v >> 16) & 0xFFu), sc, a[2]);
    a[3] = fmaf((float)(v >> 24), sc, a[3]);
}

// Fused launch: blocks [0,NCHUNK) bin edges (8192/chunk); [NCHUNK,NCHUNK+GEMMB)
// do MFMA GEMM + quantize (q8 biased-uint8; scl = rowmax/127, no dinv yet).
__global__ __launch_bounds__(256) void k_fused(const float* __restrict__ x,
                                               const float* __restrict__ W,
                                               const int* __restrict__ eidx,
                                               int* __restrict__ cursor,
                                               unsigned int* __restrict__ bins,
                                               unsigned int* __restrict__ q8,
                                               float* __restrict__ scl) {
    __shared__ uint4 SMEM[3072];          // 48KB shared by both roles
    __shared__ float s_scale[128];
    __shared__ float s_part[256];
    __shared__ int s_st;
    int t = threadIdx.x;

    if (blockIdx.x < NCHUNK) {
        // ---------------- binning role (8192 edges/chunk) ----------------
        int c = blockIdx.x;
        int* lc    = (int*)SMEM;                          // [256]
        int* lbase = (int*)SMEM + 256;                    // [256]
        unsigned int* stash = (unsigned int*)SMEM + 512;  // [8192] (32KB)
        lc[t] = 0;
        if (t < 64) {
            int v = eidx[2 * t + 1];   // int64: zero high words; int32: random rows
            unsigned long long m = __ballot(v == 0);
            if (t == 0) s_st = (m == ~0ull) ? 2 : 1;
        }
        __syncthreads();
        int st = s_st;
        long base = (long)c * CHUNK_E;
        #pragma unroll
        for (int i = 0; i < 16; ++i) {
            long e0 = base + (long)(i * 256 + t) * 2;   // pair of edges
            unsigned int u0 = 0xFFFFFFFFu, u1 = 0xFFFFFFFFu;
            if (e0 < N_EDGES) {
                unsigned int r0, r1, c0, c1;
                if (st == 2) {
                    uint4 rw = *(const uint4*)&eidx[2 * e0];
                    uint4 cw = *(const uint4*)&eidx[2 * (N_EDGES + e0)];
                    r0 = rw.x; r1 = rw.z; c0 = cw.x; c1 = cw.z;
                } else {
                    uint2 rw = *(const uint2*)&eidx[e0];
                    uint2 cw = *(const uint2*)&eidx[N_EDGES + e0];
                    r0 = rw.x; r1 = rw.y; c0 = cw.x; c1 = cw.y;
                }
                u0 = r0 | (c0 << 16);
                u1 = r1 | (c1 << 16);
                atomicAdd(&lc[c0 >> 8], 1);
                atomicAdd(&lc[c1 >> 8], 1);
            }
            stash[i * 512 + 2 * t]     = u0;
            stash[i * 512 + 2 * t + 1] = u1;
        }
        __syncthreads();
        if (t < NB && lc[t] > 0) lbase[t] = atomicAdd(&cursor[t * CURS], lc[t]);
        __syncthreads();
        #pragma unroll
        for (int i = 0; i < 32; ++i) {
            unsigned int u = stash[i * 256 + t];
            if (u != 0xFFFFFFFFu) {
                int bb = u >> 24;  // col >> 8
                int pos = atomicAdd(&lbase[bb], 1);
                bins[(size_t)bb * CAP + pos] = (u & 0xFFFFu) | (((u >> 16) & 0xFFu) << 16);
            }
        }
        return;
    }

    // ---------------- GEMM role ----------------
    uint4* xs = SMEM;                     // 64 rows x 128 bf16 (16 KB)
    uint4* wsl = SMEM + 1024;             // 128 o x 128 k bf16 (32 KB)
    float* scratch = (float*)SMEM;        // epilogue: 64 x 132 f32
    int base = (blockIdx.x - NCHUNK) * 64;
    {
        int ct = t & 127, oh = (t >> 7) * 64;
        float s = 0.f;
        #pragma unroll 8
        for (int o = 0; o < 64; ++o) {
            float w = W[(size_t)(oh + o) * CH + ct];
            s += w * w;
        }
        s_part[t] = s;
        __syncthreads();
        if (t < 128) {
            float tot = s_part[t] + s_part[t + 128];
            s_scale[t] = (tot > 1.0f) ? rsqrtf(tot) : 1.0f;
        }
    }
    #pragma unroll
    for (int it = 0; it < 4; ++it) {
        int idx = it * 256 + t;
        int r = idx >> 4, c16 = idx & 15;
        int n = base + r;
        float4 v0 = make_float4(0.f, 0.f, 0.f, 0.f), v1 = v0;
        if (n < N_NODES) {
            v0 = *(const float4*)&x[(size_t)n * CH + c16 * 8];
            v1 = *(const float4*)&x[(size_t)n * CH + c16 * 8 + 4];
        }
        uint4 p;
        p.x = pack_bf16(v0.x, v0.y); p.y = pack_bf16(v0.z, v0.w);
        p.z = pack_bf16(v1.x, v1.y); p.w = pack_bf16(v1.z, v1.w);
        xs[r * 16 + (c16 ^ (r & 7))] = p;
    }
    __syncthreads();   // s_scale ready before wsl staging
    #pragma unroll
    for (int it = 0; it < 8; ++it) {
        int idx = it * 256 + t;
        int o = idx >> 4, c16 = idx & 15;
        float4 v0 = *(const float4*)&W[(size_t)o * CH + c16 * 8];
        float4 v1 = *(const float4*)&W[(size_t)o * CH + c16 * 8 + 4];
        int k0 = c16 * 8;
        v0.x *= s_scale[k0];     v0.y *= s_scale[k0 + 1];
        v0.z *= s_scale[k0 + 2]; v0.w *= s_scale[k0 + 3];
        v1.x *= s_scale[k0 + 4]; v1.y *= s_scale[k0 + 5];
        v1.z *= s_scale[k0 + 6]; v1.w *= s_scale[k0 + 7];
        uint4 p;
        p.x = pack_bf16(v0.x, v0.y); p.y = pack_bf16(v0.z, v0.w);
        p.z = pack_bf16(v1.x, v1.y); p.w = pack_bf16(v1.z, v1.w);
        wsl[o * 16 + (c16 ^ (o & 7))] = p;
    }
    __syncthreads();
    int w = t >> 6, l = t & 63;
    int lrow = w * 16 + (l & 15);
    int hi = l >> 4;
    bf16x8 a[4];
    #pragma unroll
    for (int ks = 0; ks < 4; ++ks) {
        int c16 = ks * 4 + hi;
        a[ks] = __builtin_bit_cast(bf16x8, xs[lrow * 16 + (c16 ^ (lrow & 7))]);
    }
    float vals[8][4];
    #pragma unroll
    for (int tc = 0; tc < 8; ++tc) {
        int col = tc * 16 + (l & 15);
        f32x4 acc = {0.f, 0.f, 0.f, 0.f};
        #pragma unroll
        for (int ks = 0; ks < 4; ++ks) {
            int c16 = ks * 4 + hi;
            bf16x8 bf = __builtin_bit_cast(bf16x8, wsl[col * 16 + (c16 ^ (col & 7))]);
            acc = __builtin_amdgcn_mfma_f32_16x16x32_bf16(a[ks], bf, acc, 0, 0, 0);
        }
        #pragma unroll
        for (int r = 0; r < 4; ++r) vals[tc][r] = acc[r];
    }
    __syncthreads();
    #pragma unroll
    for (int tc = 0; tc < 8; ++tc) {
        int col = tc * 16 + (l & 15);
        #pragma unroll
        for (int r = 0; r < 4; ++r) {
            int rl = w * 16 + hi * 4 + r;
            scratch[rl * 132 + col] = vals[tc][r];
        }
    }
    __syncthreads();
    int rl = t >> 2, q = t & 3;
    const float4* rp = (const float4*)&scratch[rl * 132 + q * 32];
    float4 f[8];
    float m = 0.f;
    #pragma unroll
    for (int k = 0; k < 8; ++k) {
        f[k] = rp[k];
        m = fmaxf(m, fmaxf(fmaxf(fabsf(f[k].x), fabsf(f[k].y)),
                           fmaxf(fabsf(f[k].z), fabsf(f[k].w))));
    }
    m = fmaxf(m, __shfl_xor(m, 1));
    m = fmaxf(m, __shfl_xor(m, 2));
    float sc = m * (1.0f / 127.0f);
    float inv = (m > 0.f) ? (127.0f / m) : 0.f;
    int n = base + rl;
    if (n < N_NODES) {
        unsigned int u[8];
        #pragma unroll
        for (int k = 0; k < 8; ++k) {
            int b0 = __float2int_rn(f[k].x * inv) + 128;
            int b1 = __float2int_rn(f[k].y * inv) + 128;
            int b2 = __float2int_rn(f[k].z * inv) + 128;
            int b3 = __float2int_rn(f[k].w * inv) + 128;
            u[k] = (unsigned int)b0 | ((unsigned int)b1 << 8) |
                   ((unsigned int)b2 << 16) | ((unsigned int)b3 << 24);
        }
        uint4* qp = (uint4*)&q8[(size_t)n * 32 + q * 8];
        qp[0] = make_uint4(u[0], u[1], u[2], u[3]);
        qp[1] = make_uint4(u[4], u[5], u[6], u[7]);
        if (q == 0) scl[n] = sc;
    }
}

// per-bucket: CSR base via LDS scan of cursor; histogram colLow -> rowptr/dinv;
// scl[n] *= dinv[n] (final per-row scale); scatter bins -> src.
__global__ __launch_bounds__(256) void k_sort(const unsigned int* __restrict__ bins,
                                              const int* __restrict__ cursor,
                                              int* __restrict__ rowptr,
                                              float* __restrict__ dinv,
                                              float* __restrict__ scl,
                                              int* __restrict__ src) {
    __shared__ int shA[256], shB[256], shC[256];
    __shared__ int s_g0, s_sz;
    int t = threadIdx.x, b = blockIdx.x;
    int v = (t < NB) ? cursor[t * CURS] : 0;
    shC[t] = v;
    __syncthreads();
    for (int off = 1; off < 256; off <<= 1) {
        int u = (t >= off) ? shC[t - off] : 0;
        __syncthreads();
        shC[t] += u;
        __syncthreads();
    }
    if (t == b) { s_g0 = shC[t] - v; s_sz = v; }
    __syncthreads();
    int g0 = s_g0, sz = s_sz;
    const unsigned int* reg = bins + (size_t)b * CAP;
    shA[t] = 0;   // ldeg
    __syncthreads();
    for (int i = t; i < sz; i += 256) {
        unsigned int p = reg[i];
        atomicAdd(&shA[(p >> 16) & 255], 1);
    }
    __syncthreads();
    int d = shA[t];
    shC[t] = d;
    __syncthreads();
    for (int off = 1; off < 256; off <<= 1) {
        int u = (t >= off) ? shC[t - off] : 0;
        __syncthreads();
        shC[t] += u;
        __syncthreads();
    }
    int local_rp = g0 + shC[t] - d;
    int n = (b << 8) + t;
    if (n < N_NODES) {
        rowptr[n] = local_rp;
        float dv = rsqrtf((float)(d + 1));
        dinv[n] = dv;
        scl[n] *= dv;    // scl now final: rowmax/127 * dinv[row]
    }
    if (b == NB - 1 && t == 0) rowptr[N_NODES] = N_EDGES;
    shB[t] = local_rp;  // lcur
    __syncthreads();
    for (int i = t; i < sz; i += 256) {
        unsigned int p = reg[i];
        int pos = atomicAdd(&shB[(p >> 16) & 255], 1);
        src[pos] = (int)(p & 0xFFFFu);
    }
}

// wave per node; 8 lanes per edge, lane loads uint4 (16B = 16 channels).
// Fixed PF=6 batch prefetch: all src+scl, then all q8 (6 L3 transactions in
// flight), then FMA. Invalid batches load row 0 (broadcast, L1-hot). Tail loop
// handles deg > 48 (<0.5% of nodes at Poisson lambda=32).
__global__ __launch_bounds__(256) void k_gather(const int* __restrict__ rowptr,
                                                const int* __restrict__ src,
                                                const uint4* __restrict__ q8v,
                                                const float* __restrict__ scl,
                                                const float* __restrict__ dinv,
                                                const float* __restrict__ b,
                                                float* __restrict__ out) {
    int t = threadIdx.x;
    int wid = t >> 6, l = t & 63;
    int g = l >> 3;       // edge slot 0..7
    int c8 = l & 7;       // channel group (16 ch each)
    int n = blockIdx.x * 4 + wid;
    if (n >= N_NODES) return;
    int j0 = rowptr[n], j1 = rowptr[n + 1];
    float acc[16];
    #pragma unroll
    for (int i = 0; i < 16; ++i) acc[i] = 0.f;
    float asum = 0.f;
    int sA[PF];
    float scA[PF];
    #pragma unroll
    for (int k = 0; k < PF; ++k) {
        int e = j0 + 8 * k + g;
        bool v = e < j1;
        int s = v ? src[e] : 0;
        sA[k] = s;
        scA[k] = v ? scl[s] : 0.f;
    }
    uint4 qA[PF];
    #pragma unroll
    for (int k = 0; k < PF; ++k) qA[k] = q8v[(size_t)sA[k] * 8 + c8];
    #pragma unroll
    for (int k = 0; k < PF; ++k) {
        float sc = scA[k];
        asum += sc;
        acc4(qA[k].x, sc, &acc[0]);  acc4(qA[k].y, sc, &acc[4]);
        acc4(qA[k].z, sc, &acc[8]);  acc4(qA[k].w, sc, &acc[12]);
    }
    for (int jj = j0 + PF * 8; jj < j1; jj += 8) {   // rare: deg > 48
        int e = jj + g;
        bool v = e < j1;
        int s = v ? src[e] : 0;
        float sc = v ? scl[s] : 0.f;
        uint4 q = q8v[(size_t)s * 8 + c8];
        asum += sc;
        acc4(q.x, sc, &acc[0]);  acc4(q.y, sc, &acc[4]);
        acc4(q.z, sc, &acc[8]);  acc4(q.w, sc, &acc[12]);
    }
    #pragma unroll
    for (int i = 0; i < 16; ++i) {
        acc[i] += __shfl_xor(acc[i], 8);
        acc[i] += __shfl_xor(acc[i], 16);
        acc[i] += __shfl_xor(acc[i], 32);
    }
    asum += __shfl_xor(asum, 8);
    asum += __shfl_xor(asum, 16);
    asum += __shfl_xor(asum, 32);
    if (l < 8) {           // lane l covers channels l*16 .. l*16+15 (c8 == l)
        float di = dinv[n];
        float scn = scl[n];          // final: rowmax/127 * dinv[n]
        uint4 sv = q8v[(size_t)n * 8 + c8];
        float bias128 = 128.0f * asum;
        const float4* bp = (const float4*)&b[c8 * 16];
        float4* op = (float4*)&out[(size_t)n * CH + c8 * 16];
        unsigned int svw[4] = {sv.x, sv.y, sv.z, sv.w};
        #pragma unroll
        for (int w4 = 0; w4 < 4; ++w4) {
            unsigned int v = svw[w4];
            float4 bv = bp[w4];
            float4 o;
            o.x = (acc[w4 * 4 + 0] - bias128 + ((float)(v & 0xFFu) - 128.f) * scn) * di + bv.x;
            o.y = (acc[w4 * 4 + 1] - bias128 + ((float)((v >> 8) & 0xFFu) - 128.f) * scn) * di + bv.y;
            o.z = (acc[w4 * 4 + 2] - bias128 + ((float)((v >> 16) & 0xFFu) - 128.f) * scn) * di + bv.z;
            o.w = (acc[w4 * 4 + 3] - bias128 + ((float)(v >> 24) - 128.f) * scn) * di + bv.w;
            op[w4] = o;
        }
    }
}

extern "C" void kernel_launch(void* const* d_in, const int* in_sizes, int n_in,
                              void* d_out, int out_size, void* d_ws, size_t ws_size,
                              hipStream_t stream) {
    const float* x = (const float*)d_in[0];
    const int* eidx = (const int*)d_in[1];
    const float* W = (const float*)d_in[2];
    const float* b = (const float*)d_in[3];
    float* out = (float*)d_out;

    char* ws = (char*)d_ws;
    int*   cursor        = (int*)(ws + WS_CURSOR);
    int*   rowptr        = (int*)(ws + WS_ROWPTR);
    float* dinv          = (float*)(ws + WS_DINV);
    float* sclp          = (float*)(ws + WS_SCL);
    int*   srcarr        = (int*)(ws + WS_SRC);
    unsigned int* q8     = (unsigned int*)(ws + WS_Q8);
    unsigned int* bins   = (unsigned int*)(ws + WS_BINS);

    hipMemsetAsync(cursor, 0, NB * CURS * sizeof(int), stream);
    k_fused<<<NCHUNK + GEMMB, 256, 0, stream>>>(x, W, eidx, cursor, bins, q8, sclp);
    k_sort<<<NB, 256, 0, stream>>>(bins, cursor, rowptr, dinv, sclp, srcarr);
    k_gather<<<(N_NODES + 3) / 4, 256, 0, stream>>>(rowptr, srcarr, (const uint4*)q8,
                                                    sclp, dinv, b, out);
}

// Round 18
// 99.488 us; speedup vs baseline: 1.1471x; 1.1471x over previous
//
#include <hip/hip_runtime.h>

#define N_NODES 50000
#define N_EDGES 1600000
#define CH 128
#define NB 196         // buckets of 256 nodes: bucket = col >> 8
#define CHUNK_E 8192
#define NCHUNK 196     // ceil(N_EDGES / CHUNK_E)
#define GEMMB 782      // ceil(N_NODES / 64)
#define CAP 12288      // per-bucket region capacity (mean 8163, +45 sigma)
#define CURS 16        // cursor stride (ints): one counter per 64B line

// ws layout (bytes), total ~23 MB:
#define WS_CURSOR  0         // cursor [NB*CURS] int (padded; zeroed per call)
#define WS_ROWPTR  16384     // rowptr [N+1] int
#define WS_DINV    216448    // dinv [N] f32
#define WS_SCL     416448    // scl [N] f32 (rowmax/127; k_sort folds dinv in)
#define WS_SRC     616448    // src [E] int (6.4MB, global CSR order)
#define WS_Q8      7016448   // q8 [N][128] biased-uint8 (6.4MB)
#define WS_BINS    13416448  // bins [NB][CAP] u32 = row | colLow<<16 (9.6MB)

typedef __bf16 bf16x8 __attribute__((ext_vector_type(8)));
typedef float f32x4 __attribute__((ext_vector_type(4)));

__device__ __forceinline__ unsigned int pack_bf16(float a, float b) {
    unsigned int ua = __builtin_bit_cast(unsigned int, a);
    unsigned int ub = __builtin_bit_cast(unsigned int, b);
    ua = (ua + 0x7FFFu + ((ua >> 16) & 1u)) >> 16;   // RNE
    ub = (ub + 0x7FFFu + ((ub >> 16) & 1u)) >> 16;
    return ua | (ub << 16);
}

__device__ __forceinline__ void acc4(unsigned int v, float sc, float* a) {
    a[0] = fmaf((float)(v & 0xFFu), sc, a[0]);          // v_cvt_f32_ubyte0
    a[1] = fmaf((float)((v >> 8) & 0xFFu), sc, a[1]);
    a[2] = fmaf((float)((v >> 16) & 0xFFu), sc, a[2]);
    a[3] = fmaf((float)(v >> 24), sc, a[3]);
}

// Fused launch: blocks [0,NCHUNK) bin edges (8192/chunk); [NCHUNK,NCHUNK+GEMMB)
// do MFMA GEMM + quantize (q8 biased-uint8; scl = rowmax/127, no dinv yet).
__global__ __launch_bounds__(256) void k_fused(const float* __restrict__ x,
                                               const float* __restrict__ W,
                                               const int* __restrict__ eidx,
                                               int* __restrict__ cursor,
                                               unsigned int* __restrict__ bins,
                                               unsigned int* __restrict__ q8,
                                               float* __restrict__ scl) {
    __shared__ uint4 SMEM[3072];          // 48KB shared by both roles
    __shared__ float s_scale[128];
    __shared__ float s_part[256];
    __shared__ int s_st;
    int t = threadIdx.x;

    if (blockIdx.x < NCHUNK) {
        // ---------------- binning role (8192 edges/chunk) ----------------
        int c = blockIdx.x;
        int* lc    = (int*)SMEM;                          // [256]
        int* lbase = (int*)SMEM + 256;                    // [256]
        unsigned int* stash = (unsigned int*)SMEM + 512;  // [8192] (32KB)
        lc[t] = 0;
        if (t < 64) {
            int v = eidx[2 * t + 1];   // int64: zero high words; int32: random rows
            unsigned long long m = __ballot(v == 0);
            if (t == 0) s_st = (m == ~0ull) ? 2 : 1;
        }
        __syncthreads();
        int st = s_st;
        long base = (long)c * CHUNK_E;
        #pragma unroll
        for (int i = 0; i < 16; ++i) {
            long e0 = base + (long)(i * 256 + t) * 2;   // pair of edges
            unsigned int u0 = 0xFFFFFFFFu, u1 = 0xFFFFFFFFu;
            if (e0 < N_EDGES) {
                unsigned int r0, r1, c0, c1;
                if (st == 2) {
                    uint4 rw = *(const uint4*)&eidx[2 * e0];
                    uint4 cw = *(const uint4*)&eidx[2 * (N_EDGES + e0)];
                    r0 = rw.x; r1 = rw.z; c0 = cw.x; c1 = cw.z;
                } else {
                    uint2 rw = *(const uint2*)&eidx[e0];
                    uint2 cw = *(const uint2*)&eidx[N_EDGES + e0];
                    r0 = rw.x; r1 = rw.y; c0 = cw.x; c1 = cw.y;
                }
                u0 = r0 | (c0 << 16);
                u1 = r1 | (c1 << 16);
                atomicAdd(&lc[c0 >> 8], 1);
                atomicAdd(&lc[c1 >> 8], 1);
            }
            stash[i * 512 + 2 * t]     = u0;
            stash[i * 512 + 2 * t + 1] = u1;
        }
        __syncthreads();
        if (t < NB && lc[t] > 0) lbase[t] = atomicAdd(&cursor[t * CURS], lc[t]);
        __syncthreads();
        #pragma unroll
        for (int i = 0; i < 32; ++i) {
            unsigned int u = stash[i * 256 + t];
            if (u != 0xFFFFFFFFu) {
                int bb = u >> 24;  // col >> 8
                int pos = atomicAdd(&lbase[bb], 1);
                bins[(size_t)bb * CAP + pos] = (u & 0xFFFFu) | (((u >> 16) & 0xFFu) << 16);
            }
        }
        return;
    }

    // ---------------- GEMM role ----------------
    uint4* xs = SMEM;                     // 64 rows x 128 bf16 (16 KB)
    uint4* wsl = SMEM + 1024;             // 128 o x 128 k bf16 (32 KB)
    float* scratch = (float*)SMEM;        // epilogue: 64 x 132 f32
    int base = (blockIdx.x - NCHUNK) * 64;
    {
        int ct = t & 127, oh = (t >> 7) * 64;
        float s = 0.f;
        #pragma unroll 8
        for (int o = 0; o < 64; ++o) {
            float w = W[(size_t)(oh + o) * CH + ct];
            s += w * w;
        }
        s_part[t] = s;
        __syncthreads();
        if (t < 128) {
            float tot = s_part[t] + s_part[t + 128];
            s_scale[t] = (tot > 1.0f) ? rsqrtf(tot) : 1.0f;
        }
    }
    #pragma unroll
    for (int it = 0; it < 4; ++it) {
        int idx = it * 256 + t;
        int r = idx >> 4, c16 = idx & 15;
        int n = base + r;
        float4 v0 = make_float4(0.f, 0.f, 0.f, 0.f), v1 = v0;
        if (n < N_NODES) {
            v0 = *(const float4*)&x[(size_t)n * CH + c16 * 8];
            v1 = *(const float4*)&x[(size_t)n * CH + c16 * 8 + 4];
        }
        uint4 p;
        p.x = pack_bf16(v0.x, v0.y); p.y = pack_bf16(v0.z, v0.w);
        p.z = pack_bf16(v1.x, v1.y); p.w = pack_bf16(v1.z, v1.w);
        xs[r * 16 + (c16 ^ (r & 7))] = p;
    }
    __syncthreads();   // s_scale ready before wsl staging
    #pragma unroll
    for (int it = 0; it < 8; ++it) {
        int idx = it * 256 + t;
        int o = idx >> 4, c16 = idx & 15;
        float4 v0 = *(const float4*)&W[(size_t)o * CH + c16 * 8];
        float4 v1 = *(const float4*)&W[(size_t)o * CH + c16 * 8 + 4];
        int k0 = c16 * 8;
        v0.x *= s_scale[k0];     v0.y *= s_scale[k0 + 1];
        v0.z *= s_scale[k0 + 2]; v0.w *= s_scale[k0 + 3];
        v1.x *= s_scale[k0 + 4]; v1.y *= s_scale[k0 + 5];
        v1.z *= s_scale[k0 + 6]; v1.w *= s_scale[k0 + 7];
        uint4 p;
        p.x = pack_bf16(v0.x, v0.y); p.y = pack_bf16(v0.z, v0.w);
        p.z = pack_bf16(v1.x, v1.y); p.w = pack_bf16(v1.z, v1.w);
        wsl[o * 16 + (c16 ^ (o & 7))] = p;
    }
    __syncthreads();
    int w = t >> 6, l = t & 63;
    int lrow = w * 16 + (l & 15);
    int hi = l >> 4;
    bf16x8 a[4];
    #pragma unroll
    for (int ks = 0; ks < 4; ++ks) {
        int c16 = ks * 4 + hi;
        a[ks] = __builtin_bit_cast(bf16x8, xs[lrow * 16 + (c16 ^ (lrow & 7))]);
    }
    float vals[8][4];
    #pragma unroll
    for (int tc = 0; tc < 8; ++tc) {
        int col = tc * 16 + (l & 15);
        f32x4 acc = {0.f, 0.f, 0.f, 0.f};
        #pragma unroll
        for (int ks = 0; ks < 4; ++ks) {
            int c16 = ks * 4 + hi;
            bf16x8 bf = __builtin_bit_cast(bf16x8, wsl[col * 16 + (c16 ^ (col & 7))]);
            acc = __builtin_amdgcn_mfma_f32_16x16x32_bf16(a[ks], bf, acc, 0, 0, 0);
        }
        #pragma unroll
        for (int r = 0; r < 4; ++r) vals[tc][r] = acc[r];
    }
    __syncthreads();
    #pragma unroll
    for (int tc = 0; tc < 8; ++tc) {
        int col = tc * 16 + (l & 15);
        #pragma unroll
        for (int r = 0; r < 4; ++r) {
            int rl = w * 16 + hi * 4 + r;
            scratch[rl * 132 + col] = vals[tc][r];
        }
    }
    __syncthreads();
    int rl = t >> 2, q = t & 3;
    const float4* rp = (const float4*)&scratch[rl * 132 + q * 32];
    float4 f[8];
    float m = 0.f;
    #pragma unroll
    for (int k = 0; k < 8; ++k) {
        f[k] = rp[k];
        m = fmaxf(m, fmaxf(fmaxf(fabsf(f[k].x), fabsf(f[k].y)),
                           fmaxf(fabsf(f[k].z), fabsf(f[k].w))));
    }
    m = fmaxf(m, __shfl_xor(m, 1));
    m = fmaxf(m, __shfl_xor(m, 2));
    float sc = m * (1.0f / 127.0f);
    float inv = (m > 0.f) ? (127.0f / m) : 0.f;
    int n = base + rl;
    if (n < N_NODES) {
        unsigned int u[8];
        #pragma unroll
        for (int k = 0; k < 8; ++k) {
            int b0 = __float2int_rn(f[k].x * inv) + 128;
            int b1 = __float2int_rn(f[k].y * inv) + 128;
            int b2 = __float2int_rn(f[k].z * inv) + 128;
            int b3 = __float2int_rn(f[k].w * inv) + 128;
            u[k] = (unsigned int)b0 | ((unsigned int)b1 << 8) |
                   ((unsigned int)b2 << 16) | ((unsigned int)b3 << 24);
        }
        uint4* qp = (uint4*)&q8[(size_t)n * 32 + q * 8];
        qp[0] = make_uint4(u[0], u[1], u[2], u[3]);
        qp[1] = make_uint4(u[4], u[5], u[6], u[7]);
        if (q == 0) scl[n] = sc;
    }
}

// per-bucket: CSR base via LDS scan of cursor; histogram colLow -> rowptr/dinv;
// scl[n] *= dinv[n] (final per-row scale); scatter bins -> src.
__global__ __launch_bounds__(256) void k_sort(const unsigned int* __restrict__ bins,
                                              const int* __restrict__ cursor,
                                              int* __restrict__ rowptr,
                                              float* __restrict__ dinv,
                                              float* __restrict__ scl,
                                              int* __restrict__ src) {
    __shared__ int shA[256], shB[256], shC[256];
    __shared__ int s_g0, s_sz;
    int t = threadIdx.x, b = blockIdx.x;
    int v = (t < NB) ? cursor[t * CURS] : 0;
    shC[t] = v;
    __syncthreads();
    for (int off = 1; off < 256; off <<= 1) {
        int u = (t >= off) ? shC[t - off] : 0;
        __syncthreads();
        shC[t] += u;
        __syncthreads();
    }
    if (t == b) { s_g0 = shC[t] - v; s_sz = v; }
    __syncthreads();
    int g0 = s_g0, sz = s_sz;
    const unsigned int* reg = bins + (size_t)b * CAP;
    shA[t] = 0;   // ldeg
    __syncthreads();
    for (int i = t; i < sz; i += 256) {
        unsigned int p = reg[i];
        atomicAdd(&shA[(p >> 16) & 255], 1);
    }
    __syncthreads();
    int d = shA[t];
    shC[t] = d;
    __syncthreads();
    for (int off = 1; off < 256; off <<= 1) {
        int u = (t >= off) ? shC[t - off] : 0;
        __syncthreads();
        shC[t] += u;
        __syncthreads();
    }
    int local_rp = g0 + shC[t] - d;
    int n = (b << 8) + t;
    if (n < N_NODES) {
        rowptr[n] = local_rp;
        float dv = rsqrtf((float)(d + 1));
        dinv[n] = dv;
        scl[n] *= dv;    // scl now final: rowmax/127 * dinv[row]
    }
    if (b == NB - 1 && t == 0) rowptr[N_NODES] = N_EDGES;
    shB[t] = local_rp;  // lcur
    __syncthreads();
    for (int i = t; i < sz; i += 256) {
        unsigned int p = reg[i];
        int pos = atomicAdd(&shB[(p >> 16) & 255], 1);
        src[pos] = (int)(p & 0xFFFFu);
    }
}

// wave per node; 8 lanes per edge, each lane loads uint4 (16B = 16 channels).
// One dwordx4 wave-load covers 8 edges' full 128B rows; 2 batches in flight.
// VGPR 32 — occupancy-optimal (R12/R13/R17 all showed VGPR>32 variants lose).
__global__ __launch_bounds__(256) void k_gather(const int* __restrict__ rowptr,
                                                const int* __restrict__ src,
                                                const uint4* __restrict__ q8v,
                                                const float* __restrict__ scl,
                                                const float* __restrict__ dinv,
                                                const float* __restrict__ b,
                                                float* __restrict__ out) {
    int t = threadIdx.x;
    int wid = t >> 6, l = t & 63;
    int g = l >> 3;       // edge slot 0..7
    int c8 = l & 7;       // channel group (16 ch each)
    int n = blockIdx.x * 4 + wid;
    if (n >= N_NODES) return;
    int j0 = rowptr[n], j1 = rowptr[n + 1];
    float acc[16];
    #pragma unroll
    for (int i = 0; i < 16; ++i) acc[i] = 0.f;
    float asum = 0.f;
    for (int jj = j0; jj < j1; jj += 16) {
        int eA = jj + g, eB = jj + 8 + g;
        bool vA = eA < j1, vB = eB < j1;
        int sA = vA ? src[eA] : 0;
        int sB = vB ? src[eB] : 0;
        float scA = vA ? scl[sA] : 0.f;
        float scB = vB ? scl[sB] : 0.f;
        uint4 qA = q8v[(size_t)sA * 8 + c8];
        uint4 qB = q8v[(size_t)sB * 8 + c8];
        asum += scA + scB;
        acc4(qA.x, scA, &acc[0]);  acc4(qA.y, scA, &acc[4]);
        acc4(qA.z, scA, &acc[8]);  acc4(qA.w, scA, &acc[12]);
        acc4(qB.x, scB, &acc[0]);  acc4(qB.y, scB, &acc[4]);
        acc4(qB.z, scB, &acc[8]);  acc4(qB.w, scB, &acc[12]);
    }
    #pragma unroll
    for (int i = 0; i < 16; ++i) {
        acc[i] += __shfl_xor(acc[i], 8);
        acc[i] += __shfl_xor(acc[i], 16);
        acc[i] += __shfl_xor(acc[i], 32);
    }
    asum += __shfl_xor(asum, 8);
    asum += __shfl_xor(asum, 16);
    asum += __shfl_xor(asum, 32);
    if (l < 8) {           // lane l covers channels l*16 .. l*16+15 (c8 == l)
        float di = dinv[n];
        float scn = scl[n];          // final: rowmax/127 * dinv[n]
        uint4 sv = q8v[(size_t)n * 8 + c8];
        float bias128 = 128.0f * asum;
        const float4* bp = (const float4*)&b[c8 * 16];
        float4* op = (float4*)&out[(size_t)n * CH + c8 * 16];
        unsigned int svw[4] = {sv.x, sv.y, sv.z, sv.w};
        #pragma unroll
        for (int w4 = 0; w4 < 4; ++w4) {
            unsigned int v = svw[w4];
            float4 bv = bp[w4];
            float4 o;
            o.x = (acc[w4 * 4 + 0] - bias128 + ((float)(v & 0xFFu) - 128.f) * scn) * di + bv.x;
            o.y = (acc[w4 * 4 + 1] - bias128 + ((float)((v >> 8) & 0xFFu) - 128.f) * scn) * di + bv.y;
            o.z = (acc[w4 * 4 + 2] - bias128 + ((float)((v >> 16) & 0xFFu) - 128.f) * scn) * di + bv.z;
            o.w = (acc[w4 * 4 + 3] - bias128 + ((float)(v >> 24) - 128.f) * scn) * di + bv.w;
            op[w4] = o;
        }
    }
}

extern "C" void kernel_launch(void* const* d_in, const int* in_sizes, int n_in,
                              void* d_out, int out_size, void* d_ws, size_t ws_size,
                              hipStream_t stream) {
    const float* x = (const float*)d_in[0];
    const int* eidx = (const int*)d_in[1];
    const float* W = (const float*)d_in[2];
    const float* b = (const float*)d_in[3];
    float* out = (float*)d_out;

    char* ws = (char*)d_ws;
    int*   cursor        = (int*)(ws + WS_CURSOR);
    int*   rowptr        = (int*)(ws + WS_ROWPTR);
    float* dinv          = (float*)(ws + WS_DINV);
    float* sclp          = (float*)(ws + WS_SCL);
    int*   srcarr        = (int*)(ws + WS_SRC);
    unsigned int* q8     = (unsigned int*)(ws + WS_Q8);
    unsigned int* bins   = (unsigned int*)(ws + WS_BINS);

    hipMemsetAsync(cursor, 0, NB * CURS * sizeof(int), stream);
    k_fused<<<NCHUNK + GEMMB, 256, 0, stream>>>(x, W, eidx, cursor, bins, q8, sclp);
    k_sort<<<NB, 256, 0, stream>>>(bins, cursor, rowptr, dinv, sclp, srcarr);
    k_gather<<<(N_NODES + 3) / 4, 256, 0, stream>>>(rowptr, srcarr, (const uint4*)q8,
                                                    sclp, dinv, b, out);
}

// Round 19
// 98.386 us; speedup vs baseline: 1.1599x; 1.0112x over previous
//
#include <hip/hip_runtime.h>

#define N_NODES 50000
#define N_EDGES 1600000
#define CH 128
#define NB 196         // buckets of 256 nodes: bucket = col >> 8
#define CHUNK_E 8192
#define NCHUNK 196     // ceil(N_EDGES / CHUNK_E)
#define GEMMB 782      // ceil(N_NODES / 64)
#define CAP 12288      // per-bucket region capacity (mean 8163, +45 sigma)
#define CURS 16        // cursor stride (ints): one counter per 64B line

// ws layout (bytes), total ~23 MB:
#define WS_CURSOR  0         // cursor [NB*CURS] int (padded; zeroed per call)
#define WS_ROWPTR  16384     // rowptr [N+1] int
#define WS_DINV    216448    // dinv [N] f32
#define WS_SCL     416448    // scl [N] f32 (rowmax/127; k_sort folds dinv in)
#define WS_SRC     616448    // src [E] int (6.4MB, global CSR order)
#define WS_Q8      7016448   // q8 [N][128] biased-uint8 (6.4MB)
#define WS_BINS    13416448  // bins [NB][CAP] u32 = row | colLow<<16 (9.6MB)

typedef __bf16 bf16x8 __attribute__((ext_vector_type(8)));
typedef float f32x4 __attribute__((ext_vector_type(4)));

__device__ __forceinline__ unsigned int pack_bf16(float a, float b) {
    unsigned int ua = __builtin_bit_cast(unsigned int, a);
    unsigned int ub = __builtin_bit_cast(unsigned int, b);
    ua = (ua + 0x7FFFu + ((ua >> 16) & 1u)) >> 16;   // RNE
    ub = (ub + 0x7FFFu + ((ub >> 16) & 1u)) >> 16;
    return ua | (ub << 16);
}

__device__ __forceinline__ void acc4(unsigned int v, float sc, float* a) {
    a[0] = fmaf((float)(v & 0xFFu), sc, a[0]);          // v_cvt_f32_ubyte0
    a[1] = fmaf((float)((v >> 8) & 0xFFu), sc, a[1]);
    a[2] = fmaf((float)((v >> 16) & 0xFFu), sc, a[2]);
    a[3] = fmaf((float)(v >> 24), sc, a[3]);
}

// Fused launch: blocks [0,NCHUNK) bin edges (8192/chunk); [NCHUNK,NCHUNK+GEMMB)
// do MFMA GEMM + quantize (q8 biased-uint8; scl = rowmax/127, no dinv yet).
__global__ __launch_bounds__(256) void k_fused(const float* __restrict__ x,
                                               const float* __restrict__ W,
                                               const int* __restrict__ eidx,
                                               int* __restrict__ cursor,
                                               unsigned int* __restrict__ bins,
                                               unsigned int* __restrict__ q8,
                                               float* __restrict__ scl) {
    __shared__ uint4 SMEM[3072];          // 48KB shared by both roles
    __shared__ float s_scale[128];
    __shared__ float s_part[256];
    __shared__ int s_st;
    int t = threadIdx.x;

    if (blockIdx.x < NCHUNK) {
        // ---------------- binning role (8192 edges/chunk) ----------------
        int c = blockIdx.x;
        int* lc    = (int*)SMEM;                          // [256]
        int* lbase = (int*)SMEM + 256;                    // [256]
        unsigned int* stash = (unsigned int*)SMEM + 512;  // [8192] (32KB)
        lc[t] = 0;
        if (t < 64) {
            int v = eidx[2 * t + 1];   // int64: zero high words; int32: random rows
            unsigned long long m = __ballot(v == 0);
            if (t == 0) s_st = (m == ~0ull) ? 2 : 1;
        }
        __syncthreads();
        int st = s_st;
        long base = (long)c * CHUNK_E;
        #pragma unroll
        for (int i = 0; i < 16; ++i) {
            long e0 = base + (long)(i * 256 + t) * 2;   // pair of edges
            unsigned int u0 = 0xFFFFFFFFu, u1 = 0xFFFFFFFFu;
            if (e0 < N_EDGES) {
                unsigned int r0, r1, c0, c1;
                if (st == 2) {
                    uint4 rw = *(const uint4*)&eidx[2 * e0];
                    uint4 cw = *(const uint4*)&eidx[2 * (N_EDGES + e0)];
                    r0 = rw.x; r1 = rw.z; c0 = cw.x; c1 = cw.z;
                } else {
                    uint2 rw = *(const uint2*)&eidx[e0];
                    uint2 cw = *(const uint2*)&eidx[N_EDGES + e0];
                    r0 = rw.x; r1 = rw.y; c0 = cw.x; c1 = cw.y;
                }
                u0 = r0 | (c0 << 16);
                u1 = r1 | (c1 << 16);
                atomicAdd(&lc[c0 >> 8], 1);
                atomicAdd(&lc[c1 >> 8], 1);
            }
            stash[i * 512 + 2 * t]     = u0;
            stash[i * 512 + 2 * t + 1] = u1;
        }
        __syncthreads();
        if (t < NB && lc[t] > 0) lbase[t] = atomicAdd(&cursor[t * CURS], lc[t]);
        __syncthreads();
        #pragma unroll
        for (int i = 0; i < 32; ++i) {
            unsigned int u = stash[i * 256 + t];
            if (u != 0xFFFFFFFFu) {
                int bb = u >> 24;  // col >> 8
                int pos = atomicAdd(&lbase[bb], 1);
                bins[(size_t)bb * CAP + pos] = (u & 0xFFFFu) | (((u >> 16) & 0xFFu) << 16);
            }
        }
        return;
    }

    // ---------------- GEMM role ----------------
    uint4* xs = SMEM;                     // 64 rows x 128 bf16 (16 KB)
    uint4* wsl = SMEM + 1024;             // 128 o x 128 k bf16 (32 KB)
    float* scratch = (float*)SMEM;        // epilogue: 64 x 132 f32
    int base = (blockIdx.x - NCHUNK) * 64;
    {
        int ct = t & 127, oh = (t >> 7) * 64;
        float s = 0.f;
        #pragma unroll 8
        for (int o = 0; o < 64; ++o) {
            float w = W[(size_t)(oh + o) * CH + ct];
            s += w * w;
        }
        s_part[t] = s;
        __syncthreads();
        if (t < 128) {
            float tot = s_part[t] + s_part[t + 128];
            s_scale[t] = (tot > 1.0f) ? rsqrtf(tot) : 1.0f;
        }
    }
    #pragma unroll
    for (int it = 0; it < 4; ++it) {
        int idx = it * 256 + t;
        int r = idx >> 4, c16 = idx & 15;
        int n = base + r;
        float4 v0 = make_float4(0.f, 0.f, 0.f, 0.f), v1 = v0;
        if (n < N_NODES) {
            v0 = *(const float4*)&x[(size_t)n * CH + c16 * 8];
            v1 = *(const float4*)&x[(size_t)n * CH + c16 * 8 + 4];
        }
        uint4 p;
        p.x = pack_bf16(v0.x, v0.y); p.y = pack_bf16(v0.z, v0.w);
        p.z = pack_bf16(v1.x, v1.y); p.w = pack_bf16(v1.z, v1.w);
        xs[r * 16 + (c16 ^ (r & 7))] = p;
    }
    __syncthreads();   // s_scale ready before wsl staging
    #pragma unroll
    for (int it = 0; it < 8; ++it) {
        int idx = it * 256 + t;
        int o = idx >> 4, c16 = idx & 15;
        float4 v0 = *(const float4*)&W[(size_t)o * CH + c16 * 8];
        float4 v1 = *(const float4*)&W[(size_t)o * CH + c16 * 8 + 4];
        int k0 = c16 * 8;
        v0.x *= s_scale[k0];     v0.y *= s_scale[k0 + 1];
        v0.z *= s_scale[k0 + 2]; v0.w *= s_scale[k0 + 3];
        v1.x *= s_scale[k0 + 4]; v1.y *= s_scale[k0 + 5];
        v1.z *= s_scale[k0 + 6]; v1.w *= s_scale[k0 + 7];
        uint4 p;
        p.x = pack_bf16(v0.x, v0.y); p.y = pack_bf16(v0.z, v0.w);
        p.z = pack_bf16(v1.x, v1.y); p.w = pack_bf16(v1.z, v1.w);
        wsl[o * 16 + (c16 ^ (o & 7))] = p;
    }
    __syncthreads();
    int w = t >> 6, l = t & 63;
    int lrow = w * 16 + (l & 15);
    int hi = l >> 4;
    bf16x8 a[4];
    #pragma unroll
    for (int ks = 0; ks < 4; ++ks) {
        int c16 = ks * 4 + hi;
        a[ks] = __builtin_bit_cast(bf16x8, xs[lrow * 16 + (c16 ^ (lrow & 7))]);
    }
    float vals[8][4];
    #pragma unroll
    for (int tc = 0; tc < 8; ++tc) {
        int col = tc * 16 + (l & 15);
        f32x4 acc = {0.f, 0.f, 0.f, 0.f};
        #pragma unroll
        for (int ks = 0; ks < 4; ++ks) {
            int c16 = ks * 4 + hi;
            bf16x8 bf = __builtin_bit_cast(bf16x8, wsl[col * 16 + (c16 ^ (col & 7))]);
            acc = __builtin_amdgcn_mfma_f32_16x16x32_bf16(a[ks], bf, acc, 0, 0, 0);
        }
        #pragma unroll
        for (int r = 0; r < 4; ++r) vals[tc][r] = acc[r];
    }
    __syncthreads();
    #pragma unroll
    for (int tc = 0; tc < 8; ++tc) {
        int col = tc * 16 + (l & 15);
        #pragma unroll
        for (int r = 0; r < 4; ++r) {
            int rl = w * 16 + hi * 4 + r;
            scratch[rl * 132 + col] = vals[tc][r];
        }
    }
    __syncthreads();
    int rl = t >> 2, q = t & 3;
    const float4* rp = (const float4*)&scratch[rl * 132 + q * 32];
    float4 f[8];
    float m = 0.f;
    #pragma unroll
    for (int k = 0; k < 8; ++k) {
        f[k] = rp[k];
        m = fmaxf(m, fmaxf(fmaxf(fabsf(f[k].x), fabsf(f[k].y)),
                           fmaxf(fabsf(f[k].z), fabsf(f[k].w))));
    }
    m = fmaxf(m, __shfl_xor(m, 1));
    m = fmaxf(m, __shfl_xor(m, 2));
    float sc = m * (1.0f / 127.0f);
    float inv = (m > 0.f) ? (127.0f / m) : 0.f;
    int n = base + rl;
    if (n < N_NODES) {
        unsigned int u[8];
        #pragma unroll
        for (int k = 0; k < 8; ++k) {
            int b0 = __float2int_rn(f[k].x * inv) + 128;
            int b1 = __float2int_rn(f[k].y * inv) + 128;
            int b2 = __float2int_rn(f[k].z * inv) + 128;
            int b3 = __float2int_rn(f[k].w * inv) + 128;
            u[k] = (unsigned int)b0 | ((unsigned int)b1 << 8) |
                   ((unsigned int)b2 << 16) | ((unsigned int)b3 << 24);
        }
        uint4* qp = (uint4*)&q8[(size_t)n * 32 + q * 8];
        qp[0] = make_uint4(u[0], u[1], u[2], u[3]);
        qp[1] = make_uint4(u[4], u[5], u[6], u[7]);
        if (q == 0) scl[n] = sc;
    }
}

// per-bucket: CSR base via LDS scan of cursor; histogram colLow -> rowptr/dinv;
// scl[n] *= dinv[n] (final per-row scale); scatter bins -> src.
__global__ __launch_bounds__(256) void k_sort(const unsigned int* __restrict__ bins,
                                              const int* __restrict__ cursor,
                                              int* __restrict__ rowptr,
                                              float* __restrict__ dinv,
                                              float* __restrict__ scl,
                                              int* __restrict__ src) {
    __shared__ int shA[256], shB[256], shC[256];
    __shared__ int s_g0, s_sz;
    int t = threadIdx.x, b = blockIdx.x;
    int v = (t < NB) ? cursor[t * CURS] : 0;
    shC[t] = v;
    __syncthreads();
    for (int off = 1; off < 256; off <<= 1) {
        int u = (t >= off) ? shC[t - off] : 0;
        __syncthreads();
        shC[t] += u;
        __syncthreads();
    }
    if (t == b) { s_g0 = shC[t] - v; s_sz = v; }
    __syncthreads();
    int g0 = s_g0, sz = s_sz;
    const unsigned int* reg = bins + (size_t)b * CAP;
    shA[t] = 0;   // ldeg
    __syncthreads();
    for (int i = t; i < sz; i += 256) {
        unsigned int p = reg[i];
        atomicAdd(&shA[(p >> 16) & 255], 1);
    }
    __syncthreads();
    int d = shA[t];
    shC[t] = d;
    __syncthreads();
    for (int off = 1; off < 256; off <<= 1) {
        int u = (t >= off) ? shC[t - off] : 0;
        __syncthreads();
        shC[t] += u;
        __syncthreads();
    }
    int local_rp = g0 + shC[t] - d;
    int n = (b << 8) + t;
    if (n < N_NODES) {
        rowptr[n] = local_rp;
        float dv = rsqrtf((float)(d + 1));
        dinv[n] = dv;
        scl[n] *= dv;    // scl now final: rowmax/127 * dinv[row]
    }
    if (b == NB - 1 && t == 0) rowptr[N_NODES] = N_EDGES;
    shB[t] = local_rp;  // lcur
    __syncthreads();
    for (int i = t; i < sz; i += 256) {
        unsigned int p = reg[i];
        int pos = atomicAdd(&shB[(p >> 16) & 255], 1);
        src[pos] = (int)(p & 0xFFFFu);
    }
}

// ONE WAVE PER BLOCK (64 threads), one node per block: single-wave workgroups
// pack at wave granularity -> residency toward 8 waves/SIMD (vs 66% with
// 256-thread blocks). 8 lanes/edge, lane loads uint4; 2 batches in flight.
__global__ __launch_bounds__(64) void k_gather(const int* __restrict__ rowptr,
                                               const int* __restrict__ src,
                                               const uint4* __restrict__ q8v,
                                               const float* __restrict__ scl,
                                               const float* __restrict__ dinv,
                                               const float* __restrict__ b,
                                               float* __restrict__ out) {
    int l = threadIdx.x;
    int g = l >> 3;       // edge slot 0..7
    int c8 = l & 7;       // channel group (16 ch each)
    int n = blockIdx.x;
    int j0 = rowptr[n], j1 = rowptr[n + 1];
    float acc[16];
    #pragma unroll
    for (int i = 0; i < 16; ++i) acc[i] = 0.f;
    float asum = 0.f;
    for (int jj = j0; jj < j1; jj += 16) {
        int eA = jj + g, eB = jj + 8 + g;
        bool vA = eA < j1, vB = eB < j1;
        int sA = vA ? src[eA] : 0;
        int sB = vB ? src[eB] : 0;
        float scA = vA ? scl[sA] : 0.f;
        float scB = vB ? scl[sB] : 0.f;
        uint4 qA = q8v[(size_t)sA * 8 + c8];
        uint4 qB = q8v[(size_t)sB * 8 + c8];
        asum += scA + scB;
        acc4(qA.x, scA, &acc[0]);  acc4(qA.y, scA, &acc[4]);
        acc4(qA.z, scA, &acc[8]);  acc4(qA.w, scA, &acc[12]);
        acc4(qB.x, scB, &acc[0]);  acc4(qB.y, scB, &acc[4]);
        acc4(qB.z, scB, &acc[8]);  acc4(qB.w, scB, &acc[12]);
    }
    #pragma unroll
    for (int i = 0; i < 16; ++i) {
        acc[i] += __shfl_xor(acc[i], 8);
        acc[i] += __shfl_xor(acc[i], 16);
        acc[i] += __shfl_xor(acc[i], 32);
    }
    asum += __shfl_xor(asum, 8);
    asum += __shfl_xor(asum, 16);
    asum += __shfl_xor(asum, 32);
    if (l < 8) {           // lane l covers channels l*16 .. l*16+15 (c8 == l)
        float di = dinv[n];
        float scn = scl[n];          // final: rowmax/127 * dinv[n]
        uint4 sv = q8v[(size_t)n * 8 + c8];
        float bias128 = 128.0f * asum;
        const float4* bp = (const float4*)&b[c8 * 16];
        float4* op = (float4*)&out[(size_t)n * CH + c8 * 16];
        unsigned int svw[4] = {sv.x, sv.y, sv.z, sv.w};
        #pragma unroll
        for (int w4 = 0; w4 < 4; ++w4) {
            unsigned int v = svw[w4];
            float4 bv = bp[w4];
            float4 o;
            o.x = (acc[w4 * 4 + 0] - bias128 + ((float)(v & 0xFFu) - 128.f) * scn) * di + bv.x;
            o.y = (acc[w4 * 4 + 1] - bias128 + ((float)((v >> 8) & 0xFFu) - 128.f) * scn) * di + bv.y;
            o.z = (acc[w4 * 4 + 2] - bias128 + ((float)((v >> 16) & 0xFFu) - 128.f) * scn) * di + bv.z;
            o.w = (acc[w4 * 4 + 3] - bias128 + ((float)(v >> 24) - 128.f) * scn) * di + bv.w;
            op[w4] = o;
        }
    }
}

extern "C" void kernel_launch(void* const* d_in, const int* in_sizes, int n_in,
                              void* d_out, int out_size, void* d_ws, size_t ws_size,
                              hipStream_t stream) {
    const float* x = (const float*)d_in[0];
    const int* eidx = (const int*)d_in[1];
    const float* W = (const float*)d_in[2];
    const float* b = (const float*)d_in[3];
    float* out = (float*)d_out;

    char* ws = (char*)d_ws;
    int*   cursor        = (int*)(ws + WS_CURSOR);
    int*   rowptr        = (int*)(ws + WS_ROWPTR);
    float* dinv          = (float*)(ws + WS_DINV);
    float* sclp          = (float*)(ws + WS_SCL);
    int*   srcarr        = (int*)(ws + WS_SRC);
    unsigned int* q8     = (unsigned int*)(ws + WS_Q8);
    unsigned int* bins   = (unsigned int*)(ws + WS_BINS);

    hipMemsetAsync(cursor, 0, NB * CURS * sizeof(int), stream);
    k_fused<<<NCHUNK + GEMMB, 256, 0, stream>>>(x, W, eidx, cursor, bins, q8, sclp);
    k_sort<<<NB, 256, 0, stream>>>(bins, cursor, rowptr, dinv, sclp, srcarr);
    k_gather<<<N_NODES, 64, 0, stream>>>(rowptr, srcarr, (const uint4*)q8,
                                         sclp, dinv, b, out);
}